// Round 9
// baseline (62.374 us; speedup 1.0000x reference)
//
#include <hip/hip_runtime.h>

typedef __attribute__((ext_vector_type(8))) short short8;
typedef __attribute__((ext_vector_type(4))) float f32x4;

#define D128 128

// fp32 -> bf16 round-to-nearest-even (bit pattern)
__device__ __forceinline__ unsigned short f2bf(float f) {
    unsigned int u = __float_as_uint(f);
    u += 0x7fffu + ((u >> 16) & 1u);
    return (unsigned short)(u >> 16);
}

// ---------------------------------------------------------------------------
// Pre-kernel (unchanged layout): W (fp32 [k=128][col=128]) -> bf16 fragments.
// fragment f = of*4+kk; lane l holds 8 bf16 at ws[(f*64+l)*8] =
// W[k = kk*32 + (l>>4)*8 + j][col = of*16 + (l&15)]
// Used this round as the MFMA *A*-operand: A = W^T, free dim = out-col.
// ---------------------------------------------------------------------------
__global__ __launch_bounds__(64)
void convert_w_kernel(const float* __restrict__ w, unsigned short* __restrict__ wsb) {
    int t = blockIdx.x * 64 + threadIdx.x;   // 0..2047
    int f = t >> 6;
    int l = t & 63;
    int of = f >> 2, kk = f & 3;
    int col   = of * 16 + (l & 15);
    int kbase = kk * 32 + (l >> 4) * 8;
    short8 v;
    #pragma unroll
    for (int j = 0; j < 8; ++j)
        v[j] = (short)f2bf(w[(kbase + j) * D128 + col]);
    *(short8*)(wsb + (size_t)t * 8) = v;
}

// ---------------------------------------------------------------------------
// Main kernel, swapped-operand MFMA: D = W^T · x^T.
//   mfma(A = W-frag, B = x-frag)  ->  D[out][xrow]:
//     xrow = lane&15, out = (lane>>4)*4 + reg (+16*of per fragment)
// Each lane ends up with 32 output features (8 frags x 4 consecutive cols)
// of ONE x-row. LayerNorm reduction = in-lane sum + 2 shfl_xor (16, 32).
// Stores are direct dwordx4 NT (4 consecutive cols per lane) — zero LDS,
// zero transpose, epilogue dependency chain ~3x shorter than R8.
// Block = 2 waves x 16 rows = 32 rows.
// ---------------------------------------------------------------------------
__global__ __launch_bounds__(128)
void fused_linear_ln_kernel(const float* __restrict__ x,
                            const unsigned short* __restrict__ wsb,
                            const float* __restrict__ bias,
                            float* __restrict__ out)
{
    const int tid  = threadIdx.x;
    const int lane = tid & 63;
    const int wave = tid >> 6;
    const int row  = lane & 15;    // x-row within the wave's 16-row tile
    const int g    = lane >> 4;    // 0..3: k-subgroup on load, out-subgroup on store

    const long row_base = (long)blockIdx.x * 32 + wave * 16;

    // ---- load this wave's 16 rows of x (fp32), cvt to bf16 B-fragments ----
    // x-frag kk: lane holds x[row_base + row][kk*32 + g*8 + j], j=0..7
    short8 xfrag[4];
    {
        const float* rp = x + (row_base + row) * D128 + g * 8;
        #pragma unroll
        for (int kk = 0; kk < 4; ++kk) {
            const float4* p = (const float4*)(rp + kk * 32);
            float4 v0 = p[0];
            float4 v1 = p[1];
            short8 a;
            a[0] = (short)f2bf(v0.x); a[1] = (short)f2bf(v0.y);
            a[2] = (short)f2bf(v0.z); a[3] = (short)f2bf(v0.w);
            a[4] = (short)f2bf(v1.x); a[5] = (short)f2bf(v1.y);
            a[6] = (short)f2bf(v1.z); a[7] = (short)f2bf(v1.w);
            xfrag[kk] = a;
        }
    }

    // ---- MFMA: acc[of] holds outs [of*16 + g*4 + r] of x-row `row` ----
    f32x4 acc[8];
    #pragma unroll
    for (int of = 0; of < 8; ++of) acc[of] = (f32x4){0.f, 0.f, 0.f, 0.f};

    #pragma unroll
    for (int kk = 0; kk < 4; ++kk) {
        short8 wfrag[8];
        #pragma unroll
        for (int of = 0; of < 8; ++of)
            wfrag[of] = *(const short8*)(wsb + (size_t)((of * 4 + kk) * 64 + lane) * 8);
        #pragma unroll
        for (int of = 0; of < 8; ++of)
            acc[of] = __builtin_amdgcn_mfma_f32_16x16x32_bf16(
                wfrag[of], xfrag[kk], acc[of], 0, 0, 0);
    }

    // ---- epilogue: + bias, in-lane partial sums, 2-shuffle row reduce,
    //      normalize, direct dwordx4 NT stores ----
    float s = 0.f, q = 0.f;
    #pragma unroll
    for (int of = 0; of < 8; ++of) {
        f32x4 b4 = *(const f32x4*)(bias + of * 16 + g * 4);
        acc[of] += b4;
        #pragma unroll
        for (int r = 0; r < 4; ++r) {
            float z = acc[of][r];
            s += z;
            q += z * z;
        }
    }
    // reduce across the 4 lanes holding this row (lane bits 4,5)
    s += __shfl_xor(s, 16, 64);
    s += __shfl_xor(s, 32, 64);
    q += __shfl_xor(q, 16, 64);
    q += __shfl_xor(q, 32, 64);

    float mean = s * (1.0f / 128.0f);
    float var  = q * (1.0f / 128.0f) - mean * mean;
    float rs   = rsqrtf(var + 1e-5f);

    float* op = out + (row_base + row) * D128 + g * 4;
    #pragma unroll
    for (int of = 0; of < 8; ++of) {
        f32x4 v;
        #pragma unroll
        for (int r = 0; r < 4; ++r) v[r] = (acc[of][r] - mean) * rs;
        __builtin_nontemporal_store(v, (f32x4*)(op + of * 16));
    }
}

extern "C" void kernel_launch(void* const* d_in, const int* in_sizes, int n_in,
                              void* d_out, int out_size, void* d_ws, size_t ws_size,
                              hipStream_t stream) {
    const float* x    = (const float*)d_in[0];
    const float* w    = (const float*)d_in[1];
    const float* bias = (const float*)d_in[2];
    float* out        = (float*)d_out;

    int nrows = in_sizes[0] / D128;    // 262144
    int grid  = nrows / 32;            // 8192 blocks x 32 rows (2 waves x 16)

    unsigned short* wsb = (unsigned short*)d_ws;
    hipLaunchKernelGGL(convert_w_kernel, dim3(32), dim3(64), 0, stream, w, wsb);
    hipLaunchKernelGGL(fused_linear_ln_kernel, dim3(grid), dim3(128), 0, stream,
                       x, wsb, bias, out);
}

// Round 10
// 58.657 us; speedup vs baseline: 1.0634x; 1.0634x over previous
//
#include <hip/hip_runtime.h>

typedef __attribute__((ext_vector_type(8))) short short8;
typedef __attribute__((ext_vector_type(4))) float f32x4;

#define D128 128
#define TSTRIDE 136   // f32 row stride for 4-row store buffer: 544B, 16B-aligned,
                      // 136%32==8 -> lk groups land 8 banks apart -> exact 2-way (free)

// fp32 -> bf16 round-to-nearest-even (bit pattern)
__device__ __forceinline__ unsigned short f2bf(float f) {
    unsigned int u = __float_as_uint(f);
    u += 0x7fffu + ((u >> 16) & 1u);
    return (unsigned short)(u >> 16);
}

// ---------------------------------------------------------------------------
// Pre-kernel: convert W (fp32 [k=128][col=128]) into bf16 B-fragments in ws.
// fragment f = cf*4+kk; lane l holds 8 bf16 at ws[(f*64+l)*8] =
// B[k = kk*32 + (l>>4)*8 + j][col = cf*16 + (l&15)]
// ---------------------------------------------------------------------------
__global__ __launch_bounds__(64)
void convert_w_kernel(const float* __restrict__ w, unsigned short* __restrict__ wsb) {
    int t = blockIdx.x * 64 + threadIdx.x;   // 0..2047
    int f = t >> 6;
    int l = t & 63;
    int cf = f >> 2, kk = f & 3;
    int col   = cf * 16 + (l & 15);
    int kbase = kk * 32 + (l >> 4) * 8;
    short8 v;
    #pragma unroll
    for (int j = 0; j < 8; ++j)
        v[j] = (short)f2bf(w[(kbase + j) * D128 + col]);
    *(short8*)(wsb + (size_t)t * 8) = v;
}

// ---------------------------------------------------------------------------
// Main kernel — R8 structure exactly, ONE variable changed: stores are plain
// (cached, L2/L3 write-back) instead of nontemporal. A/B test: is 2.34 TB/s
// the NT-write-path ceiling, or does the cached path stream faster / retain
// `out` dirty lines in the 256MB L3 across graph replays?
// 16 rows/wave, block = 2 waves. Per-r tiny LDS staging -> coalesced
// full-line dwordx4 wave-stores.
// ---------------------------------------------------------------------------
__global__ __launch_bounds__(128)
void fused_linear_ln_kernel(const float* __restrict__ x,
                            const unsigned short* __restrict__ wsb,
                            const float* __restrict__ bias,
                            float* __restrict__ out)
{
    __shared__ float tlb[2][4][TSTRIDE];   // 4352 B

    const int tid  = threadIdx.x;
    const int lane = tid & 63;
    const int wave = tid >> 6;
    const int lrow = lane & 15;
    const int lk   = lane >> 4;

    const long row_base = (long)blockIdx.x * 32 + wave * 16;

    // ---- load this wave's 16 rows of x (fp32), cvt to bf16 A fragments ----
    short8 afrag[4];
    {
        const float* rp = x + (row_base + lrow) * D128 + lk * 8;
        #pragma unroll
        for (int kk = 0; kk < 4; ++kk) {
            const float4* p = (const float4*)(rp + kk * 32);
            float4 v0 = p[0];
            float4 v1 = p[1];
            short8 a;
            a[0] = (short)f2bf(v0.x); a[1] = (short)f2bf(v0.y);
            a[2] = (short)f2bf(v0.z); a[3] = (short)f2bf(v0.w);
            a[4] = (short)f2bf(v1.x); a[5] = (short)f2bf(v1.y);
            a[6] = (short)f2bf(v1.z); a[7] = (short)f2bf(v1.w);
            afrag[kk] = a;
        }
    }

    float bias_v[8];
    #pragma unroll
    for (int cf = 0; cf < 8; ++cf) bias_v[cf] = bias[cf * 16 + lrow];

    // ---- MFMA: 4 k-steps x 8 col-fragments ----
    f32x4 acc[8];
    #pragma unroll
    for (int cf = 0; cf < 8; ++cf) acc[cf] = (f32x4){0.f, 0.f, 0.f, 0.f};

    #pragma unroll
    for (int kk = 0; kk < 4; ++kk) {
        short8 bfrag[8];
        #pragma unroll
        for (int cf = 0; cf < 8; ++cf)
            bfrag[cf] = *(const short8*)(wsb + (size_t)((cf * 4 + kk) * 64 + lane) * 8);
        #pragma unroll
        for (int cf = 0; cf < 8; ++cf)
            acc[cf] = __builtin_amdgcn_mfma_f32_16x16x32_bf16(
                afrag[kk], bfrag[cf], acc[cf], 0, 0, 0);
    }

    // ---- epilogue: per r, finish 4 rows (one per lk group), stage in tiny
    //      LDS buffer, store immediately as 2 coalesced cached wave-stores ----
    const int rsel = lane >> 5;          // 0/1
    const int c4   = (lane & 31) * 4;    // col start for read-back/store

    #pragma unroll
    for (int r = 0; r < 4; ++r) {
        float s = 0.f, q = 0.f;
        float zv[8];
        #pragma unroll
        for (int cf = 0; cf < 8; ++cf) {
            float z = acc[cf][r] + bias_v[cf];
            zv[cf] = z;
            s += z;
            q += z * z;
        }
        #pragma unroll
        for (int m = 1; m <= 8; m <<= 1) {
            s += __shfl_xor(s, m, 64);
            q += __shfl_xor(q, m, 64);
        }
        float mean = s * (1.0f / 128.0f);
        float var  = q * (1.0f / 128.0f) - mean * mean;
        float rs   = rsqrtf(var + 1e-5f);

        // lk group holds output row (row_base + lk*4 + r): scatter into buffer row lk
        #pragma unroll
        for (int cf = 0; cf < 8; ++cf)
            tlb[wave][lk][cf * 16 + lrow] = (zv[cf] - mean) * rs;

        // store buffer rows 0..3 -> output rows row_base + 4*j + r (cached)
        #pragma unroll
        for (int i2 = 0; i2 < 2; ++i2) {
            int j = i2 * 2 + rsel;
            f32x4 v = *(const f32x4*)&tlb[wave][j][c4];
            *(f32x4*)(out + (row_base + 4 * j + r) * D128 + c4) = v;
        }
    }
}

extern "C" void kernel_launch(void* const* d_in, const int* in_sizes, int n_in,
                              void* d_out, int out_size, void* d_ws, size_t ws_size,
                              hipStream_t stream) {
    const float* x    = (const float*)d_in[0];
    const float* w    = (const float*)d_in[1];
    const float* bias = (const float*)d_in[2];
    float* out        = (float*)d_out;

    int nrows = in_sizes[0] / D128;    // 262144
    int grid  = nrows / 32;            // 8192 blocks x 32 rows (2 waves x 16)

    unsigned short* wsb = (unsigned short*)d_ws;
    hipLaunchKernelGGL(convert_w_kernel, dim3(32), dim3(64), 0, stream, w, wsb);
    hipLaunchKernelGGL(fused_linear_ln_kernel, dim3(grid), dim3(128), 0, stream,
                       x, wsb, bias, out);
}